// Round 7
// baseline (281.465 us; speedup 1.0000x reference)
//
#include <hip/hip_runtime.h>
#include <hip/hip_fp16.h>

// LightGCN on MI355X. Gather formulation, dinv folded into data (y = dinv*x,
// fp16 128B rows, 256B-aligned buffers). CSR via LDS-staged two-phase binning.
// Gather: one wave per FOUR nodes (MLP), 8 edge slots x 8 lanes x int4.
// Layers 1-2 write only y. Layer 3 reconstructs h1,h2 (h = y*sqrt(deg)) and
// writes out = (emb + h1 + h2 + h3)/4.
//
// d_in[0]: edge_index int32 [2][1M]; d_in[1]: emb_weight fp32 [150000][64]
// d_out  : 150000x64 fp32

constexpr int kNodes     = 150000;
constexpr int kDim       = 64;
constexpr int kEdges     = 1000000;
constexpr int kEmbFloats = kNodes * kDim;            // 9,600,000
constexpr int kBkt       = (kNodes + 255) / 256;     // 586 buckets
constexpr int kBktCap    = 2048;
constexpr int kChunk     = 4096;

__device__ __forceinline__ int wave_incl_scan(int v, int lane) {
    #pragma unroll
    for (int s = 1; s < 64; s <<= 1) {
        int u = __shfl_up(v, s);
        if (lane >= s) v += u;
    }
    return v;
}

// ---------------- Phase A: bin edges by dst>>8, LDS-staged ----------------

__global__ __launch_bounds__(1024) void binA_kernel(const int* __restrict__ src,
                                                    const int* __restrict__ dst,
                                                    int* __restrict__ cur,
                                                    unsigned* __restrict__ bin) {
    __shared__ int hist[1024];
    __shared__ int cursor[1024];
    __shared__ int sexcl[1024];
    __shared__ int gstart[1024];
    __shared__ int wsum[16];
    __shared__ unsigned staged[kChunk];
    __shared__ unsigned short sbkt[kChunk];

    int t      = threadIdx.x;
    int lane   = t & 63;
    int w      = t >> 6;
    int chunk0 = blockIdx.x * kChunk;
    int n      = min(kChunk, kEdges - chunk0);

    hist[t] = 0;
    __syncthreads();

    int myb[4], myd[4];
    #pragma unroll
    for (int j = 0; j < 4; ++j) {
        int i = j * 1024 + t;
        if (i < n) {
            int d = dst[chunk0 + i];
            myb[j] = d >> 8;
            myd[j] = d & 255;
            atomicAdd(&hist[myb[j]], 1);
        } else myb[j] = -1;
    }
    __syncthreads();

    int c   = hist[t];
    int inc = wave_incl_scan(c, lane);
    if (lane == 63) wsum[w] = inc;
    __syncthreads();
    if (w == 0) {
        int v  = (lane < 16) ? wsum[lane] : 0;
        int sc = wave_incl_scan(v, lane);
        if (lane < 16) wsum[lane] = sc - v;
    }
    __syncthreads();
    int excl = wsum[w] + inc - c;
    sexcl[t]  = excl;
    cursor[t] = excl;
    if (t < kBkt) gstart[t] = atomicAdd(&cur[t], c);
    __syncthreads();

    #pragma unroll
    for (int j = 0; j < 4; ++j) {
        int i = j * 1024 + t;
        if (i < n) {
            int s = src[chunk0 + i];
            unsigned pk = ((unsigned)myd[j] << 24) | (unsigned)s;
            int p = atomicAdd(&cursor[myb[j]], 1);
            staged[p] = pk;
            sbkt[p]   = (unsigned short)myb[j];
        }
    }
    __syncthreads();

    #pragma unroll
    for (int j = 0; j < 4; ++j) {
        int i = j * 1024 + t;
        if (i < n) {
            int bu = sbkt[i];
            int gp = gstart[bu] + (i - sexcl[bu]);
            if (gp < kBktCap) bin[(size_t)bu * kBktCap + gp] = staged[i];
        }
    }
}

// ---------------- exclusive scan over bucket sizes ----------------

__global__ __launch_bounds__(1024) void scan_base_kernel(const int* __restrict__ cur,
                                                         int* __restrict__ base) {
    __shared__ int wsum[16];
    int t = threadIdx.x;
    int lane = t & 63, w = t >> 6;
    int v = (t < kBkt) ? min(cur[t], kBktCap) : 0;
    int inc = wave_incl_scan(v, lane);
    if (lane == 63) wsum[w] = inc;
    __syncthreads();
    if (w == 0) {
        int x  = (lane < 16) ? wsum[lane] : 0;
        int sc = wave_incl_scan(x, lane);
        if (lane < 16) wsum[lane] = sc - x;
    }
    __syncthreads();
    if (t < kBkt) base[t] = wsum[w] + inc - v;
}

// ---------------- Phase B: per-bucket CSR build + offcnt/dinv ----------------

__global__ __launch_bounds__(256) void binB_kernel(const int* __restrict__ cur,
                                                   const int* __restrict__ base,
                                                   const unsigned* __restrict__ bin,
                                                   int* __restrict__ pairs,
                                                   int2* __restrict__ offcnt,
                                                   float* __restrict__ dinv) {
    __shared__ int lcnt[256];
    __shared__ int cursor[256];
    __shared__ int wsum[4];
    __shared__ int stage[kBktCap];

    int b = blockIdx.x;
    int t = threadIdx.x;
    int lane = t & 63, w = t >> 6;
    int cnt = min(cur[b], kBktCap);
    int bs  = base[b];
    const unsigned* mybin = bin + (size_t)b * kBktCap;

    lcnt[t] = 0;
    __syncthreads();
    for (int i = t; i < cnt; i += 256) atomicAdd(&lcnt[mybin[i] >> 24], 1);
    __syncthreads();

    int c   = lcnt[t];
    int inc = wave_incl_scan(c, lane);
    if (lane == 63) wsum[w] = inc;
    __syncthreads();
    if (t == 0) {
        int a = 0;
        #pragma unroll
        for (int k = 0; k < 4; ++k) { int v = wsum[k]; wsum[k] = a; a += v; }
    }
    __syncthreads();
    int excl = wsum[w] + inc - c;

    int node = (b << 8) + t;
    if (node < kNodes) {
        offcnt[node] = make_int2(bs + excl, c);
        dinv[node]   = (c > 0) ? rsqrtf((float)c) : 0.0f;
    }
    cursor[t] = excl;
    __syncthreads();

    for (int i = t; i < cnt; i += 256) {
        unsigned v = mybin[i];
        int p = atomicAdd(&cursor[v >> 24], 1);
        stage[p] = (int)(v & 0x00FFFFFFu);
    }
    __syncthreads();
    for (int i = t; i < cnt; i += 256) pairs[bs + i] = stage[i];
}

// ---------------- prescale: y0 = fp16(emb * dinv), int4 stores ----------------

__global__ __launch_bounds__(256) void prescale_kernel(const float4* __restrict__ emb4,
                                                       const float* __restrict__ dinv,
                                                       int4* __restrict__ y4) {
    int i = blockIdx.x * 256 + threadIdx.x;      // int4 index = 8 dims
    if (i >= kEmbFloats / 8) return;
    int node = i >> 3;
    float dv = dinv[node];
    float4 v0 = emb4[(size_t)i * 2];
    float4 v1 = emb4[(size_t)i * 2 + 1];
    __half2 p0 = __floats2half2_rn(v0.x * dv, v0.y * dv);
    __half2 p1 = __floats2half2_rn(v0.z * dv, v0.w * dv);
    __half2 p2 = __floats2half2_rn(v1.x * dv, v1.y * dv);
    __half2 p3 = __floats2half2_rn(v1.z * dv, v1.w * dv);
    int4 wv;
    wv.x = *reinterpret_cast<int*>(&p0); wv.y = *reinterpret_cast<int*>(&p1);
    wv.z = *reinterpret_cast<int*>(&p2); wv.w = *reinterpret_cast<int*>(&p3);
    y4[i] = wv;
}

// ---------------- gather: one wave per 4 nodes, 8 slots x int4 ----------------

__device__ __forceinline__ void acc8(float* s, int4 r) {
    float2 f0 = __half22float2(*reinterpret_cast<__half2*>(&r.x));
    float2 f1 = __half22float2(*reinterpret_cast<__half2*>(&r.y));
    float2 f2 = __half22float2(*reinterpret_cast<__half2*>(&r.z));
    float2 f3 = __half22float2(*reinterpret_cast<__half2*>(&r.w));
    s[0] += f0.x; s[1] += f0.y; s[2] += f1.x; s[3] += f1.y;
    s[4] += f2.x; s[5] += f2.y; s[6] += f3.x; s[7] += f3.y;
}

__global__ __launch_bounds__(256, 4) void gather_kernel(const int2* __restrict__ offcnt,
                                                        const int* __restrict__ pairs,
                                                        const __half* __restrict__ x16,
                                                        const float* __restrict__ dinv,
                                                        __half* __restrict__ yOut,
                                                        const float4* __restrict__ emb4,
                                                        const __half* __restrict__ y1,
                                                        const __half* __restrict__ y2,
                                                        float4* __restrict__ out4,
                                                        int mode) {
    int t    = blockIdx.x * 256 + threadIdx.x;
    int wv   = t >> 6;
    int lane = t & 63;
    int n0   = wv << 2;                 // 4 consecutive nodes per wave
    int q    = lane & 7;
    int g    = lane >> 3;

    // one 32B-wide load covers offcnt for all 4 nodes
    int2 oc = offcnt[n0 + (lane & 3)];
    int b[4], cn[4];
    #pragma unroll
    for (int j = 0; j < 4; ++j) { b[j] = __shfl(oc.x, j); cn[j] = __shfl(oc.y, j); }

    // prefetch first pairs window for all 4 nodes (independent loads)
    int mysrc[4];
    #pragma unroll
    for (int j = 0; j < 4; ++j) {
        int m0 = min(cn[j], 64);
        mysrc[j] = (lane < m0) ? pairs[b[j] + lane] : 0;
    }

    float s[4][8] = {{0.f}};
    int maxc = max(max(cn[0], cn[1]), max(cn[2], cn[3]));

    if (maxc <= 16) {
        // fast path (~99.8% of waves): 2 slot-rounds, all 8 row loads issued
        // before any decode/accumulate (dummy row 0 when slot inactive).
        int4 r0[4], r1[4];
        bool a0[4], a1[4];
        #pragma unroll
        for (int j = 0; j < 4; ++j) {
            int si0 = __shfl(mysrc[j], g);
            int si1 = __shfl(mysrc[j], g + 8);
            a0[j] = (g     < cn[j]);
            a1[j] = (g + 8 < cn[j]);
            int c0 = a0[j] ? si0 : 0;
            int c1 = a1[j] ? si1 : 0;
            r0[j] = ((const int4*)(x16 + (size_t)c0 * kDim))[q];
            r1[j] = ((const int4*)(x16 + (size_t)c1 * kDim))[q];
        }
        #pragma unroll
        for (int j = 0; j < 4; ++j) {
            if (a0[j]) acc8(s[j], r0[j]);
            if (a1[j]) acc8(s[j], r1[j]);
        }
    } else {
        // generic path: per node, windows of 64 edges, 8 slots per round
        #pragma unroll
        for (int j = 0; j < 4; ++j) {
            int c = cn[j];
            int curp = mysrc[j];
            int base = 0;
            while (true) {
                int m = c - base;
                if (m > 64) m = 64;
                for (int i = 0; i < m; i += 8) {
                    int slot = i + g;
                    int si = __shfl(curp, slot);
                    if (slot < m) {
                        int4 r = ((const int4*)(x16 + (size_t)si * kDim))[q];
                        acc8(s[j], r);
                    }
                }
                base += 64;
                if (base >= c) break;
                int mm = c - base;
                if (mm > 64) mm = 64;
                curp = (lane < mm) ? pairs[b[j] + base + lane] : 0;
            }
        }
    }

    // reduce across the 8 edge slots (xor lane bits 3..5)
    #pragma unroll
    for (int j = 0; j < 4; ++j) {
        #pragma unroll
        for (int k = 0; k < 8; ++k) {
            s[j][k] += __shfl_xor(s[j][k], 8);
            s[j][k] += __shfl_xor(s[j][k], 16);
            s[j][k] += __shfl_xor(s[j][k], 32);
        }
    }

    if (g == 0) {
        #pragma unroll
        for (int j = 0; j < 4; ++j) {
            int node = n0 + j;
            float dv = dinv[node];
            if (mode == 0) {
                float dv2 = dv * dv;
                __half2 p0 = __floats2half2_rn(s[j][0] * dv2, s[j][1] * dv2);
                __half2 p1 = __floats2half2_rn(s[j][2] * dv2, s[j][3] * dv2);
                __half2 p2 = __floats2half2_rn(s[j][4] * dv2, s[j][5] * dv2);
                __half2 p3 = __floats2half2_rn(s[j][6] * dv2, s[j][7] * dv2);
                int4 wvv;
                wvv.x = *reinterpret_cast<int*>(&p0);
                wvv.y = *reinterpret_cast<int*>(&p1);
                wvv.z = *reinterpret_cast<int*>(&p2);
                wvv.w = *reinterpret_cast<int*>(&p3);
                ((int4*)(yOut + (size_t)node * kDim))[q] = wvv;
            } else {
                float sq = sqrtf((float)cn[j]);      // = 1/dinv (0 if deg 0)
                float dvv = dv;
                size_t i4 = (size_t)node * 16 + (size_t)q * 2;
                int4 r1 = ((const int4*)(y1 + (size_t)node * kDim))[q];
                int4 r2 = ((const int4*)(y2 + (size_t)node * kDim))[q];
                float4 e0 = emb4[i4];
                float4 e1 = emb4[i4 + 1];
                float2 a0 = __half22float2(*reinterpret_cast<__half2*>(&r1.x));
                float2 a1 = __half22float2(*reinterpret_cast<__half2*>(&r1.y));
                float2 a2 = __half22float2(*reinterpret_cast<__half2*>(&r1.z));
                float2 a3 = __half22float2(*reinterpret_cast<__half2*>(&r1.w));
                float2 c0 = __half22float2(*reinterpret_cast<__half2*>(&r2.x));
                float2 c1 = __half22float2(*reinterpret_cast<__half2*>(&r2.y));
                float2 c2 = __half22float2(*reinterpret_cast<__half2*>(&r2.z));
                float2 c3 = __half22float2(*reinterpret_cast<__half2*>(&r2.w));
                float4 o0, o1;
                o0.x = (e0.x + (a0.x + c0.x) * sq + s[j][0] * dvv) * 0.25f;
                o0.y = (e0.y + (a0.y + c0.y) * sq + s[j][1] * dvv) * 0.25f;
                o0.z = (e0.z + (a1.x + c1.x) * sq + s[j][2] * dvv) * 0.25f;
                o0.w = (e0.w + (a1.y + c1.y) * sq + s[j][3] * dvv) * 0.25f;
                o1.x = (e1.x + (a2.x + c2.x) * sq + s[j][4] * dvv) * 0.25f;
                o1.y = (e1.y + (a2.y + c2.y) * sq + s[j][5] * dvv) * 0.25f;
                o1.z = (e1.z + (a3.x + c3.x) * sq + s[j][6] * dvv) * 0.25f;
                o1.w = (e1.w + (a3.y + c3.y) * sq + s[j][7] * dvv) * 0.25f;
                out4[i4]     = o0;
                out4[i4 + 1] = o1;
            }
        }
    }
}

// ---------------- launch ----------------

extern "C" void kernel_launch(void* const* d_in, const int* in_sizes, int n_in,
                              void* d_out, int out_size, void* d_ws, size_t ws_size,
                              hipStream_t stream) {
    const int*   edge  = (const int*)d_in[0];
    const int*   src   = edge;
    const int*   dst   = edge + kEdges;
    const float* emb_w = (const float*)d_in[1];
    float*       out   = (float*)d_out;

    // Workspace layout — ALL offsets multiples of 256 (sector alignment):
    //   cur     : @0          4,096
    //   binBase : @4096       4,096
    //   offcnt  : @8192       1,200,128
    //   dinv    : @1208320    600,064
    //   pairs   : @1808384    4,000,000
    //   bin     : @5808384    4,800,512
    //   y0      : @10608896   19,200,000
    //   yA      : @29808896   19,200,000
    //   yB      : @49008896   19,200,000   (end ~68.2 MB)
    char*     ws      = (char*)d_ws;
    int*      cur     = (int*)(ws);
    int*      binBase = (int*)(ws + 4096);
    int2*     offcnt  = (int2*)(ws + 8192);
    float*    dinv    = (float*)(ws + 1208320);
    int*      pairs   = (int*)(ws + 1808384);
    unsigned* bin     = (unsigned*)(ws + 5808384);
    __half*   y0      = (__half*)(ws + 10608896);
    __half*   yA      = (__half*)(ws + 29808896);
    __half*   yB      = (__half*)(ws + 49008896);

    const int binABlocks   = (kEdges + kChunk - 1) / kChunk;   // 245
    const int prescaleBlks = (kEmbFloats / 8 + 255) / 256;     // 4688
    const int gatherBlocks = kNodes / 16;                      // 9375: 4 nodes/wave

    hipMemsetAsync(cur, 0, (size_t)kBkt * 4, stream);
    binA_kernel<<<binABlocks, 1024, 0, stream>>>(src, dst, cur, bin);
    scan_base_kernel<<<1, 1024, 0, stream>>>(cur, binBase);
    binB_kernel<<<kBkt, 256, 0, stream>>>(cur, binBase, bin, pairs, offcnt, dinv);
    prescale_kernel<<<prescaleBlks, 256, 0, stream>>>((const float4*)emb_w, dinv,
                                                      (int4*)y0);

    // Layer 1: yA = fp16(dinv^2 * sum y0[src])
    gather_kernel<<<gatherBlocks, 256, 0, stream>>>(offcnt, pairs, y0, dinv,
                                                    yA, nullptr, nullptr, nullptr,
                                                    nullptr, 0);
    // Layer 2: yB = fp16(dinv^2 * sum yA[src])
    gather_kernel<<<gatherBlocks, 256, 0, stream>>>(offcnt, pairs, yA, dinv,
                                                    yB, nullptr, nullptr, nullptr,
                                                    nullptr, 0);
    // Layer 3: out = (emb + h1 + h2 + h3)/4
    gather_kernel<<<gatherBlocks, 256, 0, stream>>>(offcnt, pairs, yB, dinv,
                                                    nullptr, (const float4*)emb_w,
                                                    yA, yB, (float4*)out, 1);
}